// Round 3
// baseline (271.944 us; speedup 1.0000x reference)
//
#include <hip/hip_runtime.h>

// Length_Regulate alignment matrix.
//   repeats = (int)(durations + 0.5)   [B, T]   (durations in [1,8) => repeats in 1..8)
//   ends    = cumsum(repeats, axis=1); starts = ends - repeats (contiguous intervals)
//   out[b, t, j] = 1.0f iff starts[j] <= t < ends[j]  -> one-hot per (b,t) row.
// Output [B=32, max_len=4096, T=512] f32 = 268 MB, written exactly once -> write-BW bound.

#define T_TEXT 512
#define ROWS 32         // output rows (t values) per block; 64 KB of stores per block
#define WBLOCK 256      // writer block size

typedef float floatx4 __attribute__((ext_vector_type(4)));  // nt-store-compatible

// ---- Kernel 1: per-batch inclusive scan of rounded durations -> ends ----
__global__ void lr_scan_kernel(const float* __restrict__ dur,
                               int* __restrict__ ends) {
    __shared__ int s[T_TEXT];
    const int b = blockIdx.x;
    const int tid = threadIdx.x;          // blockDim.x == 512
    float d = dur[b * T_TEXT + tid];
    s[tid] = (int)(d + 0.5f);             // same FP op sequence as reference
    __syncthreads();
    for (int off = 1; off < T_TEXT; off <<= 1) {
        int v = s[tid];
        int add = (tid >= off) ? s[tid - off] : 0;
        __syncthreads();
        s[tid] = v + add;
        __syncthreads();
    }
    ends[b * T_TEXT + tid] = s[tid];
}

// ---- Kernel 2: stream one-hot rows out, coalesced non-temporal float4 ----
__global__ __launch_bounds__(WBLOCK) void lr_write_kernel(
        const int* __restrict__ ends_all,
        float* __restrict__ out,
        int max_len) {
    __shared__ int s_j[ROWS];

    const int b  = blockIdx.y;
    const int t0 = blockIdx.x * ROWS;
    const int tid = threadIdx.x;

    // One binary search per row, directly against the L2-resident cumsum
    // (64 KB total; re-read 32 MB across the grid -> L2 traffic only).
    // First j with ends[j] > t; contiguity gives starts[j] <= t for free.
    if (tid < ROWS) {
        const int* ends = ends_all + b * T_TEXT;
        int t = t0 + tid;
        int j = -1;
        if (t < ends[T_TEXT - 1]) {
            int lo = 0, hi = T_TEXT;
            while (lo < hi) {
                int mid = (lo + hi) >> 1;
                if (ends[mid] > t) hi = mid; else lo = mid + 1;
            }
            j = lo;
        }
        s_j[tid] = j;
    }
    __syncthreads();

    // ROWS*512 floats = ROWS*128 float4; rows contiguous -> flat vec index
    // is fully coalesced. 16 independent nt-stores per thread for ILP.
    floatx4* outv = (floatx4*)(out + ((size_t)b * max_len + t0) * T_TEXT);
    const int nvec = ROWS * (T_TEXT / 4);     // 4096
#pragma unroll
    for (int k = 0; k < nvec / WBLOCK; ++k) { // 16 iterations
        int f = tid + k * WBLOCK;
        int r = f >> 7;               // row within tile
        int c = (f & 127) << 2;       // starting column
        int j = s_j[r];
        floatx4 v = (floatx4)0.0f;
        int kk = j - c;
        if ((unsigned)kk < 4u) v[kk] = 1.0f;
        if (t0 + r < max_len) __builtin_nontemporal_store(v, outv + f);
    }
}

extern "C" void kernel_launch(void* const* d_in, const int* in_sizes, int n_in,
                              void* d_out, int out_size, void* d_ws, size_t ws_size,
                              hipStream_t stream) {
    const float* dur = (const float*)d_in[0];
    float* out = (float*)d_out;

    const int BT = in_sizes[0];           // B * T_TEXT (= 16384)
    const int B = BT / T_TEXT;            // 32
    const int max_len = out_size / BT;    // 4096

    int* ends = (int*)d_ws;               // B*T_TEXT int32 = 64 KB scratch

    lr_scan_kernel<<<B, T_TEXT, 0, stream>>>(dur, ends);

    dim3 grid((max_len + ROWS - 1) / ROWS, B);
    lr_write_kernel<<<grid, WBLOCK, 0, stream>>>(ends, out, max_len);
}